// Round 8
// baseline (25.602 us; speedup 1.0000x reference)
//
#include <hip/hip_runtime.h>

typedef __attribute__((ext_vector_type(8))) short bf16x8;
typedef __attribute__((ext_vector_type(4))) float f32x4;

union FragU { uint4 q; bf16x8 h; };

__device__ __forceinline__ unsigned short f2bf(float f) {
  unsigned u = __float_as_uint(f);
  u += 0x7FFFu + ((u >> 16) & 1u);   // RNE
  return (unsigned short)(u >> 16);
}
__device__ __forceinline__ unsigned pack2(float lo, float hi) {
  return (unsigned)f2bf(lo) | ((unsigned)f2bf(hi) << 16);
}

// ---------------------------------------------------------------------------
// kX: one-shot cast into MFMA-fragment layouts (16B unit per lane).
//   xbf : unit[((b*16+t)*8+c)*64 + l] = x[b][t*16+(l&15)][c*32+(l>>4)*8 ..+8]
//   w1f : unit[(hc*8+c)*64 + l]: col = hc*8+(fr&7) of half (fr>=8 ? B : A),
//         k = c*32+fq*8+j   (A-operand frags for kA)
//   w2f : unit[(dg*4+c)*64 + l] = W2[c*32+fq*8+j][dg*16+fr]
// Grid 560x256, branch is block-aligned (no divergence).
// ---------------------------------------------------------------------------
__global__ __launch_bounds__(256) void kX(
    const float* __restrict__ x, const float* __restrict__ W1,
    const float* __restrict__ W2, uint4* __restrict__ xbf,
    uint4* __restrict__ w1f, uint4* __restrict__ w2f)
{
  const int u = blockIdx.x * 256 + threadIdx.x;
  if (u < 131072) {            // x fragments: 16b x 16t x 8c x 64l
    const int l = u & 63, c = (u >> 6) & 7, t = (u >> 9) & 15, b = u >> 13;
    const int fr = l & 15, fq = l >> 4;
    const float* p = x + (size_t)((b * 16 + t) * 16 + fr) * 256 + c * 32 + fq * 8;
    float4 va = *(const float4*)p;
    float4 vb = *(const float4*)(p + 4);
    xbf[u] = make_uint4(pack2(va.x, va.y), pack2(va.z, va.w),
                        pack2(vb.x, vb.y), pack2(vb.z, vb.w));
  } else if (u < 139264) {     // W1 fragments: 16hc x 8c x 64l
    const int u2 = u - 131072;
    const int l = u2 & 63, c = (u2 >> 6) & 7, hc = u2 >> 9;
    const int fr = l & 15, fq = l >> 4;
    const float* p = W1 + (size_t)((fr >= 8) ? 256 : 0) * 128 +
                     (size_t)(c * 32 + fq * 8) * 128 + hc * 8 + (fr & 7);
    float v[8];
#pragma unroll
    for (int j = 0; j < 8; ++j) v[j] = p[(size_t)j * 128];
    w1f[u2] = make_uint4(pack2(v[0], v[1]), pack2(v[2], v[3]),
                         pack2(v[4], v[5]), pack2(v[6], v[7]));
  } else if (u < 143360) {     // W2 fragments: 16dg x 4c x 64l
    const int u3 = u - 139264;
    const int l = u3 & 63, c = (u3 >> 6) & 3, dg = u3 >> 8;
    const int fr = l & 15, fq = l >> 4;
    const float* p = W2 + (size_t)(c * 32 + fq * 8) * 256 + dg * 16 + fr;
    float v[8];
#pragma unroll
    for (int j = 0; j < 8; ++j) v[j] = p[(size_t)j * 256];
    w2f[u3] = make_uint4(pack2(v[0], v[1]), pack2(v[2], v[3]),
                         pack2(v[4], v[5]), pack2(v[6], v[7]));
  }
}

// ---------------------------------------------------------------------------
// kA: block (b, hc) = batch b, h-range [hc*8, hc*8+8). 1024 thr = 16 waves
// -> 16 waves/CU = 4 waves/SIMD (the round-7 fix).
// Phase 1: wave wv = m-tile wv: 8 frag loads + 8 MFMA -> As[8 h'][m] (a),
//          Cs[8 h'][m] (c + b1).  D: row n'=fq*4+g, col m=t*16+fr (validated).
// Phase 2: wave (h' = wv&7, khalf = wv>>3): R=4 rows, 32 iters of
//          broadcast ds_read_b128 + 32 VALU. khalf=1 writes partials to PB;
//          khalf=0 adds partner partials, finishes mh, writes TL (=As reuse).
// Phase 3: 256 threads pack mh rows into kB's fragment layout (mf).
// Grid (16, 16) = 256 blocks, ~25 KB LDS.
// ---------------------------------------------------------------------------
__global__ __launch_bounds__(1024) void kA(
    const uint4* __restrict__ xbf, const uint4* __restrict__ w1f,
    const float* __restrict__ b1, uint4* __restrict__ mf)
{
  __shared__ float Cs[8][260];
  __shared__ float As[8][260];   // phase 1-2: a-values; phase 3: mh (TL)
  __shared__ float PB[8][260];   // khalf=1 partial |a+c| sums

  const int tid = threadIdx.x, lane = tid & 63, wv = tid >> 6;  // wv 0..15
  const int b = blockIdx.x, hc = blockIdx.y;
  const int fr = lane & 15, fq = lane >> 4;

  FragU afr[8];
#pragma unroll
  for (int c = 0; c < 8; ++c) afr[c].q = w1f[(hc * 8 + c) * 64 + lane];

  float b1v[4];
#pragma unroll
  for (int g = 0; g < 4; ++g)
    b1v[g] = (fq >= 2) ? b1[hc * 8 + (fq - 2) * 4 + g] : 0.f;

  {  // phase 1: MFMA, wave = m-tile
    const int t = wv;
    f32x4 acc = {0.f, 0.f, 0.f, 0.f};
#pragma unroll
    for (int c = 0; c < 8; ++c) {
      FragU bfr;
      bfr.q = xbf[((size_t)(b * 16 + t) * 8 + c) * 64 + lane];
      acc = __builtin_amdgcn_mfma_f32_16x16x32_bf16(afr[c].h, bfr.h, acc, 0, 0, 0);
    }
    const int m = t * 16 + fr;
    if (fq < 2) {
#pragma unroll
      for (int g = 0; g < 4; ++g) As[fq * 4 + g][m] = acc[g];
    } else {
#pragma unroll
      for (int g = 0; g < 4; ++g) Cs[(fq - 2) * 4 + g][m] = acc[g] + b1v[g];
    }
  }
  __syncthreads();

  // phase 2
  const int hp = wv & 7, kh = wv >> 3;
  const float a0 = As[hp][lane],       a1 = As[hp][64 + lane];
  const float a2 = As[hp][128 + lane], a3 = As[hp][192 + lane];

  float sumC = 0.f;
  if (kh == 0) {
    float4 s4 = *(const float4*)&Cs[hp][lane * 4];
    sumC = (s4.x + s4.y) + (s4.z + s4.w);
#pragma unroll
    for (int off = 32; off >= 1; off >>= 1) sumC += __shfl_xor(sumC, off, 64);
  }

  float s0a = 0.f, s0b = 0.f, s1a = 0.f, s1b = 0.f;
  float s2a = 0.f, s2b = 0.f, s3a = 0.f, s3b = 0.f;
  const int u0 = kh * 32;
#pragma unroll 8
  for (int u = 0; u < 32; ++u) {
    float4 c = *(const float4*)&Cs[hp][(u0 + u) * 4];  // uniform -> broadcast
    s0a += fabsf(a0 + c.x); s0b += fabsf(a0 + c.y);
    s0a += fabsf(a0 + c.z); s0b += fabsf(a0 + c.w);
    s1a += fabsf(a1 + c.x); s1b += fabsf(a1 + c.y);
    s1a += fabsf(a1 + c.z); s1b += fabsf(a1 + c.w);
    s2a += fabsf(a2 + c.x); s2b += fabsf(a2 + c.y);
    s2a += fabsf(a2 + c.z); s2b += fabsf(a2 + c.w);
    s3a += fabsf(a3 + c.x); s3b += fabsf(a3 + c.y);
    s3a += fabsf(a3 + c.z); s3b += fabsf(a3 + c.w);
  }

  if (kh == 1) {
    PB[hp][lane]       = s0a + s0b;
    PB[hp][64 + lane]  = s1a + s1b;
    PB[hp][128 + lane] = s2a + s2b;
    PB[hp][192 + lane] = s3a + s3b;
  }
  __syncthreads();

  if (kh == 0) {
    As[hp][lane]       = (256.f * a0 + sumC + (s0a + s0b) + PB[hp][lane])       * (1.f / 512.f);
    As[hp][64 + lane]  = (256.f * a1 + sumC + (s1a + s1b) + PB[hp][64 + lane])  * (1.f / 512.f);
    As[hp][128 + lane] = (256.f * a2 + sumC + (s2a + s2b) + PB[hp][128 + lane]) * (1.f / 512.f);
    As[hp][192 + lane] = (256.f * a3 + sumC + (s3a + s3b) + PB[hp][192 + lane]) * (1.f / 512.f);
  }
  __syncthreads();

  // phase 3: row m = tid; our 8 h-values are frag elems j=0..7 of
  // unit (Tg*4 + hc>>2)*64 + (hc&3)*16 + fr
  if (tid < 256) {
    const int fr2 = tid & 15, T = tid >> 4;
    uint4 o = make_uint4(pack2(As[0][tid], As[1][tid]), pack2(As[2][tid], As[3][tid]),
                         pack2(As[4][tid], As[5][tid]), pack2(As[6][tid], As[7][tid]));
    mf[((size_t)(b * 16 + T) * 4 + (hc >> 2)) * 64 + (hc & 3) * 16 + fr2] = o;
  }
}

// ---------------------------------------------------------------------------
// kB: out[m][d] = mh[m,:]@W2[:,d] + b2[d] + x[m][d]. Pure fragment loads
// (4 A + 4 B, all 1KB contiguous) + 4 MFMA. Wave = (m-tile, d-group).
// Grid (256, 4) = 1024 blocks x 256 thr -> 4 blocks/CU, 16 waves/CU.
// ---------------------------------------------------------------------------
__global__ __launch_bounds__(256) void kB(
    const uint4* __restrict__ mf, const uint4* __restrict__ w2f,
    const float* __restrict__ b2, const float* __restrict__ x,
    float* __restrict__ out)
{
  const int tid = threadIdx.x, lane = tid & 63, wu = tid >> 6;
  const int mt = blockIdx.x;             // 0..255
  const int dg = blockIdx.y * 4 + wu;    // 0..15
  const int fr = lane & 15, fq = lane >> 4;

  f32x4 acc = {0.f, 0.f, 0.f, 0.f};
#pragma unroll
  for (int c = 0; c < 4; ++c) {
    FragU a, bb;
    a.q  = mf[((size_t)mt * 4 + c) * 64 + lane];
    bb.q = w2f[((size_t)dg * 4 + c) * 64 + lane];
    acc = __builtin_amdgcn_mfma_f32_16x16x32_bf16(a.h, bb.h, acc, 0, 0, 0);
  }

  const int d = dg * 16 + fr;
  const float bv = b2[d];
#pragma unroll
  for (int g = 0; g < 4; ++g) {
    const int m = mt * 16 + fq * 4 + g;
    const size_t o = (size_t)m * 256 + d;
    out[o] = acc[g] + bv + x[o];
  }
}

extern "C" void kernel_launch(void* const* d_in, const int* in_sizes, int n_in,
                              void* d_out, int out_size, void* d_ws, size_t ws_size,
                              hipStream_t stream) {
  const float* x  = (const float*)d_in[0];
  const float* W1 = (const float*)d_in[1];
  const float* b1 = (const float*)d_in[2];
  const float* W2 = (const float*)d_in[3];
  const float* b2 = (const float*)d_in[4];
  float* out = (float*)d_out;

  char* ws = (char*)d_ws;
  uint4* xbf = (uint4*)ws;                              // 131072 u = 2 MB
  uint4* w1f = (uint4*)(ws + (2u << 20));               // 8192 u = 128 KB
  uint4* w2f = (uint4*)(ws + (2u << 20) + (128u << 10)); // 4096 u = 64 KB
  uint4* mf  = (uint4*)(ws + (2u << 20) + (192u << 10)); // 65536 u = 1 MB

  kX<<<560, 256, 0, stream>>>(x, W1, W2, xbf, w1f, w2f);
  kA<<<dim3(16, 16), 1024, 0, stream>>>(xbf, w1f, b1, mf);
  kB<<<dim3(256, 4), 256, 0, stream>>>(mf, w2f, b2, x, out);
}